// Round 1
// baseline (99.778 us; speedup 1.0000x reference)
//
#include <hip/hip_runtime.h>

#define N_SPINS 512
#define BATCH   1024
#define BB      16    // batch rows per block
#define JT      128   // j-columns per block

// Kernel 1: build upper-triangular coupling matrix M[i][j] (f32, 512x512) from J2,
// and zero the output energies (d_out is poisoned 0xAA by the harness).
// pairs come from np.triu_indices(512, k=1) in lex order, so
//   c(i,j) = i*(N-1) - i*(i-1)/2 + (j - i - 1)   for j > i.
__global__ __launch_bounds__(256) void build_M(const float* __restrict__ J2,
                                               float* __restrict__ M,
                                               float* __restrict__ energy) {
    int idx = blockIdx.x * 256 + threadIdx.x;   // grid = 1024 blocks -> 262144 threads
    if (idx < BATCH) energy[idx] = 0.0f;
    int i = idx >> 9;          // row
    int j = idx & (N_SPINS-1); // col
    float v = 0.0f;
    if (j > i) {
        int c = i * (N_SPINS - 1) - (i * (i - 1)) / 2 + (j - i - 1);
        v = J2[c];
    }
    M[idx] = v;                // coalesced: j contiguous, c contiguous in j
}

// Kernel 2: energy[b] += sum_{j in slice} x[b,j] * (J1[j] + sum_i x[b,i] * M[i,j])
// Block = 256 threads: 2 row-groups x 128 columns. Grid = (1024/BB) x (512/JT) = 64x4.
__global__ __launch_bounds__(256) void ising_energy(const float* __restrict__ x,
                                                    const float* __restrict__ J1,
                                                    const float* __restrict__ M,
                                                    float* __restrict__ energy) {
    __shared__ float xs[BB][N_SPINS];  // 32 KB x-tile
    const int tid = threadIdx.x;
    const int b0  = blockIdx.x * BB;
    const int j0  = blockIdx.y * JT;

    // Stage x tile: 16 contiguous rows of 512 f32 = 8192 floats, float4-vectorized.
    const float4* xg  = (const float4*)(x + (size_t)b0 * N_SPINS);
    float4*       xs4 = (float4*)&xs[0][0];
    #pragma unroll
    for (int t = 0; t < (BB * N_SPINS / 4) / 256; ++t)
        xs4[tid + t * 256] = xg[tid + t * 256];
    __syncthreads();

    const int jl = tid & (JT - 1);   // 0..127
    const int rg = tid >> 7;         // 0 or 1
    const int j  = j0 + jl;
    const int r0 = rg * 8;           // 8 batch rows per thread

    float acc[8];
    #pragma unroll
    for (int r = 0; r < 8; ++r) acc[r] = 0.0f;

    // k-loop: M loads coalesced (64 consecutive j per wave); x reads are
    // wave-uniform LDS broadcasts (conflict-free).
    const float* Mc = M + j;
    #pragma unroll 4
    for (int i = 0; i < N_SPINS; ++i) {
        float m = Mc[(size_t)i * N_SPINS];
        #pragma unroll
        for (int r = 0; r < 8; ++r)
            acc[r] = fmaf(xs[r0 + r][i], m, acc[r]);
    }

    // Fused epilogue: weight by x[b,j], add this slice's J1 contribution.
    const float j1 = J1[j];
    float part[8];
    #pragma unroll
    for (int r = 0; r < 8; ++r)
        part[r] = xs[r0 + r][j] * (acc[r] + j1);

    // wave64 butterfly reduce over the 64 j's in this wave
    #pragma unroll
    for (int off = 32; off >= 1; off >>= 1) {
        #pragma unroll
        for (int r = 0; r < 8; ++r)
            part[r] += __shfl_down(part[r], off, 64);
    }

    if ((tid & 63) == 0) {  // one lane per wave: 8 atomics (device-scope f32)
        #pragma unroll
        for (int r = 0; r < 8; ++r)
            atomicAdd(&energy[b0 + r0 + r], part[r]);
    }
}

extern "C" void kernel_launch(void* const* d_in, const int* in_sizes, int n_in,
                              void* d_out, int out_size, void* d_ws, size_t ws_size,
                              hipStream_t stream) {
    const float* x  = (const float*)d_in[0];  // [1024, 512]
    const float* J1 = (const float*)d_in[1];  // [512]
    const float* J2 = (const float*)d_in[2];  // [130816]
    // d_in[3] = pairs, unused (closed-form index)
    float* M      = (float*)d_ws;             // 512*512*4 = 1 MB scratch
    float* energy = (float*)d_out;            // [1024] f32

    build_M<<<dim3((N_SPINS * N_SPINS) / 256), 256, 0, stream>>>(J2, M, energy);
    ising_energy<<<dim3(BATCH / BB, N_SPINS / JT), 256, 0, stream>>>(x, J1, M, energy);
}

// Round 2
// 75.434 us; speedup vs baseline: 1.3227x; 1.3227x over previous
//
#include <hip/hip_runtime.h>

#define NSP   512
#define BATCH 1024
#define RB    32    // batch rows per block
#define JTW   256   // j-span per block
#define KC    32    // k-chunk (i-span) per block
// 256 threads = 8 row-groups (rt) x 32 col-groups (jt); each thread: 4 rows x 8 cols

// Kernel 1: M[i][j] = J2[c(i,j)] for j>i else 0 (triu lex order), zero energies.
__global__ __launch_bounds__(256) void build_M(const float* __restrict__ J2,
                                               float* __restrict__ M,
                                               float* __restrict__ energy) {
    int idx = blockIdx.x * 256 + threadIdx.x;
    if (idx < BATCH) energy[idx] = 0.0f;
    int i = idx >> 9;
    int j = idx & (NSP - 1);
    float v = 0.0f;
    if (j > i) v = J2[i * (NSP - 1) - (i * (i - 1)) / 2 + (j - i - 1)];
    M[idx] = v;
}

// Kernel 2: energy[b] += sum_{j in jspan} x[b,j] * ([kt==0]*J1[j] + sum_{i in kchunk} x[b,i]*M[i,j])
// Grid: (32 row-tiles, 24 tile-codes). Tile-codes skip the all-zero (j<256, i>=256) region:
//   z<8  -> jtile=0 (j in [0,256)),   kt=z    (i in [0,256))
//   z>=8 -> jtile=1 (j in [256,512)), kt=z-8  (i in [0,512))
__global__ __launch_bounds__(256) void ising_energy(const float* __restrict__ x,
                                                    const float* __restrict__ J1,
                                                    const float* __restrict__ M,
                                                    float* __restrict__ energy) {
    __shared__ float xst[KC][RB];   // transposed x tile (4 KB): xst[k][row]

    const int tid = threadIdx.x;
    const int rt  = tid >> 5;       // 0..7
    const int jt  = tid & 31;       // 0..31
    const int b0  = blockIdx.x * RB;
    const int z   = blockIdx.y;
    const int jtile = (z < 8) ? 0 : 1;
    const int kt    = (z < 8) ? z : (z - 8);
    const int j0  = jtile * JTW;
    const int i0  = kt * KC;

    // Stage x tile transposed: thread t loads 4 contiguous k's of one row.
    {
        int r  = tid >> 3;          // 0..31
        int k4 = (tid & 7) * 4;     // 0..28 step 4
        float4 v = *reinterpret_cast<const float4*>(x + (size_t)(b0 + r) * NSP + i0 + k4);
        xst[k4 + 0][r] = v.x;
        xst[k4 + 1][r] = v.y;
        xst[k4 + 2][r] = v.z;
        xst[k4 + 3][r] = v.w;
    }
    __syncthreads();

    const int jb = j0 + jt * 8;     // this thread's 8 consecutive columns
    const int r0 = rt * 4;          // this thread's 4 rows (within tile)

    float acc[4][8];
    #pragma unroll
    for (int r = 0; r < 4; ++r)
        #pragma unroll
        for (int c = 0; c < 8; ++c) acc[r][c] = 0.0f;

    const float* Mp = M + (size_t)i0 * NSP + jb;
    #pragma unroll 4
    for (int i = 0; i < KC; ++i) {
        const float* mrow = Mp + (size_t)i * NSP;
        float4 m0 = *reinterpret_cast<const float4*>(mrow);
        float4 m1 = *reinterpret_cast<const float4*>(mrow + 4);
        float4 xv = *reinterpret_cast<const float4*>(&xst[i][r0]);  // broadcast within lanes
        float mv[8] = {m0.x, m0.y, m0.z, m0.w, m1.x, m1.y, m1.z, m1.w};
        float xr[4] = {xv.x, xv.y, xv.z, xv.w};
        #pragma unroll
        for (int r = 0; r < 4; ++r)
            #pragma unroll
            for (int c = 0; c < 8; ++c)
                acc[r][c] = fmaf(xr[r], mv[c], acc[r][c]);
    }

    // Epilogue: weight by x[b,j], add J1 exactly once (kt==0 blocks cover every j).
    float j1v[8];
    if (kt == 0) {
        float4 a = *reinterpret_cast<const float4*>(J1 + jb);
        float4 b = *reinterpret_cast<const float4*>(J1 + jb + 4);
        j1v[0]=a.x; j1v[1]=a.y; j1v[2]=a.z; j1v[3]=a.w;
        j1v[4]=b.x; j1v[5]=b.y; j1v[6]=b.z; j1v[7]=b.w;
    } else {
        #pragma unroll
        for (int c = 0; c < 8; ++c) j1v[c] = 0.0f;
    }

    float part[4];
    #pragma unroll
    for (int r = 0; r < 4; ++r) {
        const float* xrow = x + (size_t)(b0 + r0 + r) * NSP + jb;
        float4 a = *reinterpret_cast<const float4*>(xrow);
        float4 b = *reinterpret_cast<const float4*>(xrow + 4);
        float xw[8] = {a.x, a.y, a.z, a.w, b.x, b.y, b.z, b.w};
        float s = 0.0f;
        #pragma unroll
        for (int c = 0; c < 8; ++c) s = fmaf(xw[c], acc[r][c] + j1v[c], s);
        part[r] = s;
    }

    // Reduce over the 32 jt-lanes (each 32-lane wave half is one rt group).
    #pragma unroll
    for (int off = 16; off >= 1; off >>= 1)
        #pragma unroll
        for (int r = 0; r < 4; ++r)
            part[r] += __shfl_xor(part[r], off, 64);

    if (jt == 0) {
        #pragma unroll
        for (int r = 0; r < 4; ++r)
            atomicAdd(&energy[b0 + r0 + r], part[r]);
    }
}

extern "C" void kernel_launch(void* const* d_in, const int* in_sizes, int n_in,
                              void* d_out, int out_size, void* d_ws, size_t ws_size,
                              hipStream_t stream) {
    const float* x  = (const float*)d_in[0];  // [1024, 512]
    const float* J1 = (const float*)d_in[1];  // [512]
    const float* J2 = (const float*)d_in[2];  // [130816]
    // d_in[3] = pairs, unused (closed-form index)
    float* M      = (float*)d_ws;             // 1 MB scratch
    float* energy = (float*)d_out;            // [1024]

    build_M<<<dim3((NSP * NSP) / 256), 256, 0, stream>>>(J2, M, energy);
    ising_energy<<<dim3(BATCH / RB, 24), 256, 0, stream>>>(x, J1, M, energy);
}

// Round 3
// 75.088 us; speedup vs baseline: 1.3288x; 1.0046x over previous
//
#include <hip/hip_runtime.h>

#define NSP   512
#define BATCH 1024
#define RB    16    // batch rows per block
#define JTW   256   // j-span per block
#define KC    32    // i-chunk (k) per block
// 256 threads = 8 row-groups (rt, 2 rows each) x 32 col-groups (jt, 8 cols each)

// Kernel 1: M[i][j] = J2[c(i,j)] for j>i else 0 (triu lex order), zero energies.
__global__ __launch_bounds__(256) void build_M(const float* __restrict__ J2,
                                               float* __restrict__ M,
                                               float* __restrict__ energy) {
    int idx = blockIdx.x * 256 + threadIdx.x;
    if (idx < BATCH) energy[idx] = 0.0f;
    int i = idx >> 9;
    int j = idx & (NSP - 1);
    float v = 0.0f;
    if (j > i) v = J2[i * (NSP - 1) - (i * (i - 1)) / 2 + (j - i - 1)];
    M[idx] = v;
}

// Kernel 2: energy[b] += sum_{j in jspan} x[b,j] * ([kt==0]*J1[j] + sum_{i in kchunk} x[b,i]*M[i,j])
// Grid: (64 row-tiles, 24 tile-codes); codes skip the all-zero (j<256, i>=256) region:
//   z<8  -> jtile=0 (j in [0,256)),   kt=z    (i-chunk in [0,256))
//   z>=8 -> jtile=1 (j in [256,512)), kt=z-8  (i-chunk in [0,512))
__global__ __launch_bounds__(256) void ising_energy(const float* __restrict__ x,
                                                    const float* __restrict__ J1,
                                                    const float* __restrict__ M,
                                                    float* __restrict__ energy) {
    __shared__ float xst[KC][RB];   // transposed x tile (2 KB): xst[k][row]

    const int tid = threadIdx.x;
    const int rt  = tid >> 5;       // 0..7
    const int jt  = tid & 31;       // 0..31
    const int b0  = blockIdx.x * RB;
    const int z   = blockIdx.y;
    const int jtile = (z < 8) ? 0 : 1;
    const int kt    = (z < 8) ? z : (z - 8);
    const int j0  = jtile * JTW;
    const int i0  = kt * KC;

    // Stage x tile transposed: thread t loads 2 contiguous k's of one row.
    {
        int r  = tid >> 4;          // 0..15
        int k2 = (tid & 15) * 2;    // 0..30 step 2
        float2 v = *reinterpret_cast<const float2*>(x + (size_t)(b0 + r) * NSP + i0 + k2);
        xst[k2 + 0][r] = v.x;
        xst[k2 + 1][r] = v.y;
    }
    __syncthreads();

    const int jb = j0 + jt * 8;     // this thread's 8 consecutive columns
    const int r0 = rt * 2;          // this thread's 2 rows (within tile)

    float acc[2][8];
    #pragma unroll
    for (int r = 0; r < 2; ++r)
        #pragma unroll
        for (int c = 0; c < 8; ++c) acc[r][c] = 0.0f;

    const float* Mp = M + (size_t)i0 * NSP + jb;
    #pragma unroll 4
    for (int ii = 0; ii < KC; ++ii) {
        const float* mrow = Mp + (size_t)ii * NSP;
        float4 m0 = *reinterpret_cast<const float4*>(mrow);      // coalesced, 16B aligned
        float4 m1 = *reinterpret_cast<const float4*>(mrow + 4);
        float2 xv = *reinterpret_cast<const float2*>(&xst[ii][r0]);  // wave-broadcast LDS read
        float mv[8] = {m0.x, m0.y, m0.z, m0.w, m1.x, m1.y, m1.z, m1.w};
        float xr[2] = {xv.x, xv.y};
        #pragma unroll
        for (int r = 0; r < 2; ++r)
            #pragma unroll
            for (int c = 0; c < 8; ++c)
                acc[r][c] = fmaf(xr[r], mv[c], acc[r][c]);
    }

    // Epilogue: weight by x[b,j], add J1 exactly once (kt==0 covers every j).
    float j1v[8];
    if (kt == 0) {
        float4 a = *reinterpret_cast<const float4*>(J1 + jb);
        float4 b = *reinterpret_cast<const float4*>(J1 + jb + 4);
        j1v[0]=a.x; j1v[1]=a.y; j1v[2]=a.z; j1v[3]=a.w;
        j1v[4]=b.x; j1v[5]=b.y; j1v[6]=b.z; j1v[7]=b.w;
    } else {
        #pragma unroll
        for (int c = 0; c < 8; ++c) j1v[c] = 0.0f;
    }

    float part[2];
    #pragma unroll
    for (int r = 0; r < 2; ++r) {
        const float* xrow = x + (size_t)(b0 + r0 + r) * NSP + jb;
        float4 a = *reinterpret_cast<const float4*>(xrow);
        float4 b = *reinterpret_cast<const float4*>(xrow + 4);
        float xw[8] = {a.x, a.y, a.z, a.w, b.x, b.y, b.z, b.w};
        float s = 0.0f;
        #pragma unroll
        for (int c = 0; c < 8; ++c) s = fmaf(xw[c], acc[r][c] + j1v[c], s);
        part[r] = s;
    }

    // Reduce over the 32 jt-lanes (each wave = 2 rt-groups x 32 jt).
    #pragma unroll
    for (int off = 16; off >= 1; off >>= 1)
        #pragma unroll
        for (int r = 0; r < 2; ++r)
            part[r] += __shfl_xor(part[r], off, 64);

    if (jt == 0) {  // lanes 0 and 32 of each wave
        #pragma unroll
        for (int r = 0; r < 2; ++r)
            atomicAdd(&energy[b0 + r0 + r], part[r]);
    }
}

extern "C" void kernel_launch(void* const* d_in, const int* in_sizes, int n_in,
                              void* d_out, int out_size, void* d_ws, size_t ws_size,
                              hipStream_t stream) {
    const float* x  = (const float*)d_in[0];  // [1024, 512]
    const float* J1 = (const float*)d_in[1];  // [512]
    const float* J2 = (const float*)d_in[2];  // [130816]
    // d_in[3] = pairs, unused (closed-form index)
    float* M      = (float*)d_ws;             // 1 MB scratch
    float* energy = (float*)d_out;            // [1024]

    build_M<<<dim3((NSP * NSP) / 256), 256, 0, stream>>>(J2, M, energy);
    ising_energy<<<dim3(BATCH / RB, 24), 256, 0, stream>>>(x, J1, M, energy);
}

// Round 5
// 67.946 us; speedup vs baseline: 1.4685x; 1.1051x over previous
//
#include <hip/hip_runtime.h>

#define NSP   512
#define BATCH 1024

typedef __attribute__((ext_vector_type(8))) short bf16x8;
typedef __attribute__((ext_vector_type(4))) float f32x4;

__device__ __forceinline__ unsigned short f2bf(float f) {
    union { float f; unsigned int u; } c; c.f = f;
    unsigned int u = c.u + (0x7FFFu + ((c.u >> 16) & 1u));  // RTN-even
    return (unsigned short)(u >> 16);
}

// Kernel 1: Mt[j][i] = bf16(J2[c(i,j)]) for i<j else 0  (c = triu lex index);
// xb = bf16(x); energy = 0.
__global__ __launch_bounds__(256) void prep(const float* __restrict__ x,
                                            const float* __restrict__ J2,
                                            unsigned short* __restrict__ Mt,
                                            unsigned short* __restrict__ xb,
                                            float* __restrict__ energy) {
    int idx = blockIdx.x * 256 + threadIdx.x;   // 1024 blocks -> 262144 threads
    int j = idx >> 9;
    int i = idx & (NSP - 1);
    float v = 0.0f;
    if (i < j) v = J2[i * (NSP - 1) - (i * (i - 1)) / 2 + (j - i - 1)];
    Mt[idx] = f2bf(v);                          // Mt[j*512 + i], coalesced in i
    if (idx < (BATCH * NSP) / 4) {              // first 131072 threads: convert x
        float4 xv = reinterpret_cast<const float4*>(x)[idx];
        ushort4 o;
        o.x = f2bf(xv.x); o.y = f2bf(xv.y); o.z = f2bf(xv.z); o.w = f2bf(xv.w);
        reinterpret_cast<ushort4*>(xb)[idx] = o;
    }
    if (idx < BATCH) energy[idx] = 0.0f;
}

// Kernel 2: one wave per 16(b) x 16(j) output tile.
//   C[b][j] = sum_i xb[b,i] * Mt[j,i]  via mfma_f32_16x16x32_bf16 over k-chunks,
//   k-range truncated to the upper triangle (i < j).
//   energy[b] += sum_j x[b,j] * (C[b,j] + J1[j])
// Fragment layouts (16x16x32 bf16):
//   A: lane l holds A[row=l&15][k=(l>>4)*8 + e], e=0..7  (16B contiguous)
//   B: lane l holds B[k=(l>>4)*8 + e][col=l&15]          -> Mt[col][k..k+7] contiguous
//   D: lane l, reg r -> (row=(l>>4)*4 + r, col=l&15)     [verified m89]
__global__ __launch_bounds__(256) void ising_mfma(const float* __restrict__ x,
                                                  const float* __restrict__ J1,
                                                  const unsigned short* __restrict__ Mt,
                                                  const unsigned short* __restrict__ xb,
                                                  float* __restrict__ energy) {
    const int tid  = threadIdx.x;
    const int w    = tid >> 6;          // wave 0..3
    const int lane = tid & 63;
    const int bt   = blockIdx.x;        // 0..63  (b-tile)
    const int jt   = blockIdx.y * 4 + w;// 0..31  (j-tile, one per wave)
    const int b0   = bt * 16;
    const int j0   = jt * 16;
    const int r16  = lane & 15;
    const int kg   = lane >> 4;

    // chunks needed to cover i in [0, j0+14] (last col's max coupling partner)
    const int nch = (16 * jt + 46) >> 5;     // 1..16

    const unsigned short* Ap = xb + (size_t)(b0 + r16) * NSP + kg * 8;
    const unsigned short* Bp = Mt + (size_t)(j0 + r16) * NSP + kg * 8;

    f32x4 acc = {0.0f, 0.0f, 0.0f, 0.0f};
    #pragma unroll 4
    for (int ch = 0; ch < nch; ++ch) {
        bf16x8 a = *reinterpret_cast<const bf16x8*>(Ap + ch * 32);
        bf16x8 b = *reinterpret_cast<const bf16x8*>(Bp + ch * 32);
        acc = __builtin_amdgcn_mfma_f32_16x16x32_bf16(a, b, acc, 0, 0, 0);
    }

    // Epilogue: energy[b0+row] += x[b0+row, j] * (acc + J1[j]), reduced over 16 cols.
    const int jcol = j0 + r16;
    const float j1 = J1[jcol];
    float part[4];
    #pragma unroll
    for (int r = 0; r < 4; ++r) {
        int row = kg * 4 + r;
        float xw = x[(size_t)(b0 + row) * NSP + jcol];
        part[r] = xw * (acc[r] + j1);
    }
    #pragma unroll
    for (int off = 8; off >= 1; off >>= 1)
        #pragma unroll
        for (int r = 0; r < 4; ++r)
            part[r] += __shfl_xor(part[r], off, 64);

    if (r16 == 0) {   // lanes 0,16,32,48: rows kg*4 .. kg*4+3
        #pragma unroll
        for (int r = 0; r < 4; ++r)
            atomicAdd(&energy[b0 + kg * 4 + r], part[r]);
    }
}

extern "C" void kernel_launch(void* const* d_in, const int* in_sizes, int n_in,
                              void* d_out, int out_size, void* d_ws, size_t ws_size,
                              hipStream_t stream) {
    const float* x  = (const float*)d_in[0];  // [1024, 512]
    const float* J1 = (const float*)d_in[1];  // [512]
    const float* J2 = (const float*)d_in[2];  // [130816]
    // d_in[3] = pairs, unused (closed-form index)
    unsigned short* Mt = (unsigned short*)d_ws;                    // 512 KB
    unsigned short* xb = (unsigned short*)((char*)d_ws + 524288);  // 1 MB
    float* energy = (float*)d_out;                                 // [1024]

    prep<<<dim3((NSP * NSP) / 256), 256, 0, stream>>>(x, J2, Mt, xb, energy);
    ising_mfma<<<dim3(BATCH / 16, 8), 256, 0, stream>>>(x, J1, Mt, xb, energy);
}